// Round 13
// baseline (165.513 us; speedup 1.0000x reference)
//
#include <hip/hip_runtime.h>

#define B_  256
#define T_  256
#define S_  20
#define U1  32
#define G1  128   // 4*U1
#define U2  24
#define G2  96    // 4*U2
#define NT  16    // 16-row t-tiles per sequence

typedef __attribute__((ext_vector_type(8))) short short8;   // 8 bf16 = 4 VGPRs
typedef __attribute__((ext_vector_type(4))) float f32x4;    // MFMA acc

// Raw-HW activations (v_exp_f32 = 2^x, pre-scaled by log2e). R7: 134->74us.
__device__ __forceinline__ float sigmoidf_(float x) {
    return __builtin_amdgcn_rcpf(1.0f + __builtin_amdgcn_exp2f(x * -1.44269504f));
}
__device__ __forceinline__ float tanhf_fast(float x) {   // 1 - 2/(1+e^{2x})
    return 1.0f - 2.0f * __builtin_amdgcn_rcpf(1.0f + __builtin_amdgcn_exp2f(x * 2.88539008f));
}

__device__ __forceinline__ unsigned short f2bf(float a) {
    unsigned int u = __float_as_uint(a);
    u += 0x7FFFu + ((u >> 16) & 1u);
    return (unsigned short)(u >> 16);
}
__device__ __forceinline__ unsigned int pack2bf(float a, float b) {
    unsigned int ua = __float_as_uint(a); ua += 0x7FFFu + ((ua >> 16) & 1u);
    unsigned int ub = __float_as_uint(b); ub += 0x7FFFu + ((ub >> 16) & 1u);
    return (ua >> 16) | (ub & 0xFFFF0000u);
}
union frag_u { short8 v; unsigned int u[4]; };
union h2x  { unsigned int u32; _Float16 h[2]; };

// FUSED producer-consumer, R12 + DEDICATED CONSUMER SIMD:
// 256 threads = 4 waves = 1 wave/EU (amdgpu_waves_per_eu(1,1) pins it).
// Wave 0: produces tile 0 (~6us) then runs the outer recurrence with its
//   SIMD entirely to itself (R12's 512-thr layout co-scheduled a producer
//   on the consumer's SIMD -> ~24us of issue contention: 98 vs 74us).
// Waves 1-3: produce tiles {1,4,7,10,13}/{2,5,8,11,14}/{3,6,9,12,15} --
//   consumption order; per-tile LDS flag released (workgroup-scope atomics).
// Consumer spin-waits only when its 1-row prefetch crosses a tile boundary.
__global__ __attribute__((amdgpu_flat_work_group_size(256, 256)))
__attribute__((amdgpu_waves_per_eu(1, 1)))
void fused_kernel(
    const float* __restrict__ x,        // [B*T*S]
    const int*   __restrict__ lengths,  // [B]
    const float* __restrict__ Wi,       // [G1]
    const float* __restrict__ Ui,       // [U1*G1]
    const float* __restrict__ bi,       // [G1]
    const float* __restrict__ Wo,       // [U1*G2]
    const float* __restrict__ Uo,       // [U2*G2]
    const float* __restrict__ bo,       // [G2]
    const float* __restrict__ Wd,       // [U2]
    const float* __restrict__ bd,       // [1]
    float* __restrict__ out)            // [B]
{
    __shared__ __align__(16) _Float16      Pl[T_][G2];      // [t][u*4+g], 48 KB
    __shared__ __align__(16) unsigned short hbb[4][16][40]; // per-wave h tiles
    __shared__ unsigned int flags[NT];
    const int b    = blockIdx.x;
    const int len  = lengths[b];                 // >= 1
    const int tid  = threadIdx.x;
    const int w    = __builtin_amdgcn_readfirstlane(tid >> 6);   // wave 0..3
    const int lane = tid & 63;
    const int q    = lane >> 4;
    const int n    = lane & 15;

    if (tid < NT) flags[tid] = 0;
    __syncthreads();                             // only barrier: flag init

    // ---- one-time fragment/bias loads ----
    frag_u Bui[8];
#pragma unroll
    for (int tt = 0; tt < 8; ++tt)
#pragma unroll
        for (int k2 = 0; k2 < 4; ++k2)
            Bui[tt].u[k2] = pack2bf(Ui[(8 * q + 2 * k2) * G1 + 16 * tt + n],
                                    Ui[(8 * q + 2 * k2 + 1) * G1 + 16 * tt + n]);
    frag_u Bwo[6];
#pragma unroll
    for (int tt = 0; tt < 6; ++tt)
#pragma unroll
        for (int k2 = 0; k2 < 4; ++k2)
            Bwo[tt].u[k2] = pack2bf(Wo[(8 * q + 2 * k2) * G2 + 16 * tt + n],
                                    Wo[(8 * q + 2 * k2 + 1) * G2 + 16 * tt + n]);
    float bi_l[8], Wi_l[8], bo_l[6];
#pragma unroll
    for (int tt = 0; tt < 8; ++tt) { bi_l[tt] = bi[16 * tt + n]; Wi_l[tt] = Wi[16 * tt + n]; }
#pragma unroll
    for (int tt = 0; tt < 6; ++tt) bo_l[tt] = bo[16 * tt + n];
    // P-store targets: col=16tt+n -> (g=col/24, u=col%24) -> offset u*4+g
    int pcol[6];
#pragma unroll
    for (int tt = 0; tt < 6; ++tt) {
        const int col = 16 * tt + n;
        const int g = col / 24;
        pcol[tt] = (col - 24 * g) * 4 + g;
    }

    // ---- tile worklists (consumption order) ----
    // w0: tile 0 only. w1..w3: {w, w+3, w+6, w+9, w+12}
    const int ntl = (w == 0) ? 1 : 5;

#pragma unroll 1
    for (int i = 0; i < ntl; ++i) {
        const int tile = (w == 0) ? 0 : (w + 3 * i);
        const int wt0  = tile * 16;
        if (wt0 >= len) break;                   // list increasing: rest masked too

        const float* xr = x + (size_t)(b * T_ + wt0 + 4 * q) * S_;
        float c[2][4];
#pragma unroll
        for (int uh = 0; uh < 2; ++uh)
#pragma unroll
            for (int r = 0; r < 4; ++r) c[uh][r] = 0.0f;

        float xc[4];
#pragma unroll
        for (int r = 0; r < 4; ++r) xc[r] = xr[r * S_];

        // peeled s = 0 (h == 0: no MFMA)
        {
            f32x4 acc[8];
#pragma unroll
            for (int tt = 0; tt < 8; ++tt)
#pragma unroll
                for (int r = 0; r < 4; ++r)
                    acc[tt][r] = bi_l[tt] + xc[r] * Wi_l[tt];
#pragma unroll
            for (int uh = 0; uh < 2; ++uh)
#pragma unroll
                for (int r = 0; r < 4; ++r) {
                    const float iv = sigmoidf_(acc[0 + uh][r]);
                    const float fv = sigmoidf_(acc[2 + uh][r]);
                    const float gv = tanhf_fast(acc[4 + uh][r]);
                    const float ov = sigmoidf_(acc[6 + uh][r]);
                    c[uh][r] = fv * c[uh][r] + iv * gv;
                    hbb[w][4 * q + r][n + 16 * uh] = f2bf(ov * tanhf_fast(c[uh][r]));
                }
        }
#pragma unroll
        for (int r = 0; r < 4; ++r) xc[r] = xr[r * S_ + 1];

        // steady state s = 1..19
#pragma unroll 1
        for (int s = 1; s < S_; ++s) {
            const int sn = (s + 1 < S_) ? s + 1 : S_ - 1;
            float xnx[4];
#pragma unroll
            for (int r = 0; r < 4; ++r) xnx[r] = xr[r * S_ + sn];

            f32x4 acc[8];
#pragma unroll
            for (int tt = 0; tt < 8; ++tt)
#pragma unroll
                for (int r = 0; r < 4; ++r)
                    acc[tt][r] = bi_l[tt] + xc[r] * Wi_l[tt];

            const short8 A = *(const short8*)&hbb[w][n][8 * q];
#pragma unroll
            for (int tt = 0; tt < 8; ++tt)
                acc[tt] = __builtin_amdgcn_mfma_f32_16x16x32_bf16(A, Bui[tt].v, acc[tt], 0, 0, 0);

#pragma unroll
            for (int uh = 0; uh < 2; ++uh)
#pragma unroll
                for (int r = 0; r < 4; ++r) {
                    const float iv = sigmoidf_(acc[0 + uh][r]);
                    const float fv = sigmoidf_(acc[2 + uh][r]);
                    const float gv = tanhf_fast(acc[4 + uh][r]);
                    const float ov = sigmoidf_(acc[6 + uh][r]);
                    c[uh][r] = fv * c[uh][r] + iv * gv;
                    hbb[w][4 * q + r][n + 16 * uh] = f2bf(ov * tanhf_fast(c[uh][r]));
                }
#pragma unroll
            for (int r = 0; r < 4; ++r) xc[r] = xnx[r];
        }

        // P tile = bo + h @ Wo -> LDS, unit-major pair layout
        {
            const short8 A = *(const short8*)&hbb[w][n][8 * q];
            f32x4 accp[6];
#pragma unroll
            for (int tt = 0; tt < 6; ++tt) {
#pragma unroll
                for (int r = 0; r < 4; ++r) accp[tt][r] = bo_l[tt];
                accp[tt] = __builtin_amdgcn_mfma_f32_16x16x32_bf16(A, Bwo[tt].v, accp[tt], 0, 0, 0);
            }
#pragma unroll
            for (int r = 0; r < 4; ++r) {
                const int tr = wt0 + 4 * q + r;
#pragma unroll
                for (int tt = 0; tt < 6; ++tt)
                    Pl[tr][pcol[tt]] = (_Float16)accp[tt][r];
            }
        }
        // release tile (DS in-order; release fence)
        __hip_atomic_store(&flags[tile], 1u, __ATOMIC_RELEASE, __HIP_MEMORY_SCOPE_WORKGROUP);
    }

    if (w != 0) return;                          // producers retire

    // ======== phase 2: outer LSTM + head (wave 0, SIMD to itself) ==========
    const int half = lane >> 5;                  // 0: gates i,f  1: gates g,o
    const int sub  = lane & 31;
    const int u    = (sub < U2) ? sub : U2 - 1;

    float wA[U2], wB[U2];                        // 48 weight VGPRs, resident
#pragma unroll
    for (int k = 0; k < U2; ++k) {
        wA[k] = Uo[k * G2 + (2 * half) * U2 + u];
        wB[k] = Uo[k * G2 + (2 * half + 1) * U2 + u];
    }

    // one ds_read_b64 per row: all 4 gate pre-activations of unit u
    auto ldrow = [&](int t) -> f32x4 {
        const uint2 raw = *reinterpret_cast<const uint2*>(&Pl[t][4 * u]);
        h2x a, c2; a.u32 = raw.x; c2.u32 = raw.y;
        f32x4 r;
        r[0] = (float)a.h[0];  r[1] = (float)a.h[1];   // i, f
        r[2] = (float)c2.h[0]; r[3] = (float)c2.h[1];  // g, o
        return r;
    };

    f32x4 cur = ldrow(0);                        // tile 0 self-produced
    float cu, hu;
    {   // peeled t = 0 (h == 0, c == 0) -- all gates lane-local
        const float ig = sigmoidf_(cur[0]);
        const float gg = tanhf_fast(cur[2]);
        const float og = sigmoidf_(cur[3]);
        cu = ig * gg;
        hu = og * tanhf_fast(cu);
    }
    int wtile = 0;
    f32x4 nxt = ldrow((1 < len) ? 1 : 0);        // prefetch row for t=1

#pragma unroll 1
    for (int t = 1; t < len; ++t) {
        const int tn = (t + 1 < len) ? (t + 1) : (len - 1);
        const int ttile = tn >> 4;
        if (ttile != wtile) {                    // wave-uniform
            while (__hip_atomic_load(&flags[ttile], __ATOMIC_ACQUIRE,
                                     __HIP_MEMORY_SCOPE_WORKGROUP) == 0u)
                __builtin_amdgcn_s_sleep(1);
            wtile = ttile;
        }
        const f32x4 pf = ldrow(tn);

        float hk[U2];
#pragma unroll
        for (int k = 0; k < U2; ++k)
            hk[k] = __int_as_float(__builtin_amdgcn_readlane(__float_as_int(hu), k));

        const float pA = half ? nxt[2] : nxt[0];
        const float pB = half ? nxt[3] : nxt[1];
        float a0 = pA, a1 = 0.0f, a2 = 0.0f, a3 = 0.0f;
        float b0 = pB, b1 = 0.0f, b2 = 0.0f, b3 = 0.0f;
#pragma unroll
        for (int k = 0; k < U2; k += 4) {        // 4 chains x depth 6
            a0 += hk[k]     * wA[k];     b0 += hk[k]     * wB[k];
            a1 += hk[k + 1] * wA[k + 1]; b1 += hk[k + 1] * wB[k + 1];
            a2 += hk[k + 2] * wA[k + 2]; b2 += hk[k + 2] * wB[k + 2];
            a3 += hk[k + 3] * wA[k + 3]; b3 += hk[k + 3] * wB[k + 3];
        }
        const float zA = (a0 + a1) + (a2 + a3);  // half0: z_i ; half1: z_g
        const float zB = (b0 + b1) + (b2 + b3);  // half0: z_f ; half1: z_o
        const float oA = __shfl_xor(zA, 32);
        const float oB = __shfl_xor(zB, 32);

        const float z_i = half ? oA : zA;
        const float z_f = half ? oB : zB;
        const float z_g = half ? zA : oA;
        const float z_o = half ? zB : oB;

        const float ig = sigmoidf_(z_i);
        const float fg = sigmoidf_(z_f);
        const float gg = tanhf_fast(z_g);
        const float og = sigmoidf_(z_o);
        cu = fg * cu + ig * gg;
        hu = og * tanhf_fast(cu);                // identical on both halves

        nxt = pf;
    }

    // dense sigmoid head
    float acc = bd[0];
#pragma unroll
    for (int k = 0; k < U2; ++k)
        acc += __int_as_float(__builtin_amdgcn_readlane(__float_as_int(hu), k)) * Wd[k];
    if (lane == 0) out[b] = sigmoidf_(acc);
}

extern "C" void kernel_launch(void* const* d_in, const int* in_sizes, int n_in,
                              void* d_out, int out_size, void* d_ws, size_t ws_size,
                              hipStream_t stream) {
    const float* x       = (const float*)d_in[0];
    const int*   lengths = (const int*)  d_in[1];
    const float* Wi      = (const float*)d_in[2];
    const float* Ui      = (const float*)d_in[3];
    const float* bi      = (const float*)d_in[4];
    const float* Wo      = (const float*)d_in[5];
    const float* Uo      = (const float*)d_in[6];
    const float* bo      = (const float*)d_in[7];
    const float* Wd      = (const float*)d_in[8];
    const float* bd      = (const float*)d_in[9];
    float* out = (float*)d_out;

    fused_kernel<<<dim3(B_), dim3(256), 0, stream>>>(
        x, lengths, Wi, Ui, bi, Wo, Uo, bo, Wd, bd, out);
}